// Round 1
// baseline (503.378 us; speedup 1.0000x reference)
//
#include <hip/hip_runtime.h>

typedef unsigned short u16;
typedef __attribute__((ext_vector_type(8))) __bf16 bf16x8;
typedef __attribute__((ext_vector_type(4))) float f32x4;
typedef __attribute__((ext_vector_type(4))) unsigned short u16x4;

#define SEQ 2048
#define DM 1024
#define NH 16
#define DH 64
// M = BATCH*SEQ = 4096, N = 1024, K = 1024 for all GEMMs

__device__ __forceinline__ unsigned short f2bf(float f) {
  unsigned u = __builtin_bit_cast(unsigned, f);
  u += 0x7fffu + ((u >> 16) & 1u);
  return (unsigned short)(u >> 16);
}

__device__ __forceinline__ void gload_lds16(const u16* g, u16* l) {
  __builtin_amdgcn_global_load_lds(
      (const __attribute__((address_space(1))) u16*)g,
      (__attribute__((address_space(3))) u16*)l, 16, 0, 0);
}

// ---------- convert x fp32 -> bf16 ----------
__global__ __launch_bounds__(256) void cvt_kernel(const float* __restrict__ in,
                                                  u16* __restrict__ out, int n4) {
  int id = blockIdx.x * 256 + threadIdx.x;
  if (id >= n4) return;
  float4 v = ((const float4*)in)[id];
  u16x4 o = { f2bf(v.x), f2bf(v.y), f2bf(v.z), f2bf(v.w) };
  ((u16x4*)out)[id] = o;
}

// ---------- transpose + convert weight: Wt[n][k] = W[k][n] ----------
__global__ __launch_bounds__(256) void wtrans_kernel(const float* __restrict__ W,
                                                     u16* __restrict__ Wt) {
  __shared__ float tile[32][33];
  int tx = threadIdx.x & 31, ty = threadIdx.x >> 5; // 32 x 8
  int k0 = blockIdx.y * 32, n0 = blockIdx.x * 32;
#pragma unroll
  for (int j = 0; j < 32; j += 8)
    tile[ty + j][tx] = W[(size_t)(k0 + ty + j) * DM + n0 + tx];
  __syncthreads();
#pragma unroll
  for (int j = 0; j < 32; j += 8)
    Wt[(size_t)(n0 + ty + j) * DM + k0 + tx] = f2bf(tile[tx][ty + j]);
}

// ---------- GEMM: C = A(bf16 [4096,1024]) @ Wt^T + bias ----------
// modes: 0=Q  -> [B,H,S,DH] bf16, scaled by 0.125 (1/sqrt(DH))
//        1=K  -> [B,H,S,DH] bf16
//        2=V  -> [B,H,DH,S] bf16 (transposed for PV B-fragments)
//        3=O  -> [4096,1024] fp32 (final output)
__global__ __launch_bounds__(256) void gemm_kernel(
    const u16* __restrict__ A, const u16* __restrict__ WtBase,
    const float* __restrict__ b0, const float* __restrict__ b1,
    const float* __restrict__ b2,
    void* __restrict__ O0, void* __restrict__ O1, void* __restrict__ O2,
    int modeBase) {
  const int Kd = 1024, Nd = 1024;
  const int mode = modeBase + blockIdx.z;
  const u16* Bt = WtBase + (size_t)blockIdx.z * (1u << 20);
  const float* bias = (blockIdx.z == 0) ? b0 : (blockIdx.z == 1) ? b1 : b2;
  void* Out = (blockIdx.z == 0) ? O0 : (blockIdx.z == 1) ? O1 : O2;

  __shared__ u16 As[128 * 32];
  __shared__ u16 Bs[128 * 32];
  const int tid = threadIdx.x;
  const int lane = tid & 63, w = tid >> 6;
  const int wr = w >> 1, wc = w & 1;
  const int brow = blockIdx.y * 128, bcol = blockIdx.x * 128;

  f32x4 acc[4][4] = {};

  const int srow = tid >> 2;        // 0..63, includes wave bits
  const int scol = (tid & 3) * 8;
  const u16* a0 = A + (size_t)(brow + srow) * Kd + scol;
  const u16* a1 = A + (size_t)(brow + 64 + srow) * Kd + scol;
  const u16* bt0 = Bt + (size_t)(bcol + srow) * Kd + scol;
  const u16* bt1 = Bt + (size_t)(bcol + 64 + srow) * Kd + scol;
  u16* asl = As + w * 512; // wave-uniform LDS base; +2048 for issue 1
  u16* bsl = Bs + w * 512;

  for (int kt = 0; kt < Kd; kt += 32) {
    gload_lds16(a0 + kt, asl);
    gload_lds16(a1 + kt, asl + 2048);
    gload_lds16(bt0 + kt, bsl);
    gload_lds16(bt1 + kt, bsl + 2048);
    __syncthreads();
    bf16x8 af[4], bfr[4];
#pragma unroll
    for (int m = 0; m < 4; ++m)
      af[m] = *(const bf16x8*)(As + (wr * 64 + m * 16 + (lane & 15)) * 32 + (lane >> 4) * 8);
#pragma unroll
    for (int n = 0; n < 4; ++n)
      bfr[n] = *(const bf16x8*)(Bs + (wc * 64 + n * 16 + (lane & 15)) * 32 + (lane >> 4) * 8);
#pragma unroll
    for (int m = 0; m < 4; ++m)
#pragma unroll
      for (int n = 0; n < 4; ++n)
        acc[m][n] = __builtin_amdgcn_mfma_f32_16x16x32_bf16(af[m], bfr[n], acc[m][n], 0, 0, 0);
    __syncthreads();
  }

  const int r0 = brow + wr * 64 + (lane >> 4) * 4; // + m*16 + i
  const int c0 = bcol + wc * 64 + (lane & 15);     // + n*16
#pragma unroll
  for (int m = 0; m < 4; ++m) {
#pragma unroll
    for (int n = 0; n < 4; ++n) {
      const int col = c0 + n * 16;
      const float bv = bias[col];
      if (mode == 3) {
        float* O = (float*)Out;
#pragma unroll
        for (int i = 0; i < 4; ++i) {
          int row = r0 + m * 16 + i;
          O[(size_t)row * Nd + col] = acc[m][n][i] + bv;
        }
      } else if (mode == 2) {
        // V transposed: Vt[((b*16+h)*64+dh)*2048 + s], 4 consecutive s per thread
        const int rowb = r0 + m * 16;
        const int b = rowb >> 11, s = rowb & 2047;
        const int h = col >> 6, dh = col & 63;
        u16x4 pk;
#pragma unroll
        for (int i = 0; i < 4; ++i) pk[i] = f2bf(acc[m][n][i] + bv);
        u16* O = (u16*)Out;
        *(u16x4*)(O + ((size_t)((b * NH + h) * DH + dh) * SEQ + s)) = pk;
      } else {
        const float sc = (mode == 0) ? 0.125f : 1.0f;
        u16* O = (u16*)Out;
#pragma unroll
        for (int i = 0; i < 4; ++i) {
          int row = r0 + m * 16 + i;
          int b = row >> 11, s = row & 2047;
          int h = col >> 6, dh = col & 63;
          O[((size_t)(b * NH + h) * SEQ + s) * DH + dh] = f2bf((acc[m][n][i] + bv) * sc);
        }
      }
    }
  }
}

// ---------- causal flash attention ----------
// grid: (32 qtiles, 32 bh). 256 threads = 4 waves; wave w owns q rows qt*64+w*16..+15
__global__ __launch_bounds__(256) void attn_kernel(const u16* __restrict__ Qb,
                                                   const u16* __restrict__ Kb,
                                                   const u16* __restrict__ Vt,
                                                   u16* __restrict__ Hh) {
  const int qt = blockIdx.x, bh = blockIdx.y;
  const int tid = threadIdx.x, lane = tid & 63, w = tid >> 6;
  const int lrow = lane & 15, lk8 = (lane >> 4) * 8;
  const int q0 = qt * 64 + w * 16;

  const u16* Qp = Qb + (size_t)bh * SEQ * DH;
  const u16* Kp = Kb + (size_t)bh * SEQ * DH;
  const u16* Vp = Vt + (size_t)bh * DH * SEQ;

  bf16x8 qf[2];
#pragma unroll
  for (int ks = 0; ks < 2; ++ks)
    qf[ks] = *(const bf16x8*)(Qp + (size_t)(q0 + lrow) * DH + ks * 32 + lk8);

  float m_i[4], l_i[4];
  f32x4 hacc[4];
#pragma unroll
  for (int i = 0; i < 4; ++i) { m_i[i] = -1e30f; l_i[i] = 0.f; }
#pragma unroll
  for (int g = 0; g < 4; ++g) hacc[g] = (f32x4){0.f, 0.f, 0.f, 0.f};

  __shared__ u16 Ps[4][16 * 64];

  for (int kt = 0; kt <= qt; ++kt) {
    f32x4 s[4] = {};
#pragma unroll
    for (int ks = 0; ks < 2; ++ks) {
#pragma unroll
      for (int g = 0; g < 4; ++g) {
        bf16x8 kf = *(const bf16x8*)(Kp + (size_t)(kt * 64 + g * 16 + lrow) * DH + ks * 32 + lk8);
        s[g] = __builtin_amdgcn_mfma_f32_16x16x32_bf16(qf[ks], kf, s[g], 0, 0, 0);
      }
    }
    if (kt == qt) { // diagonal tile: causal mask
#pragma unroll
      for (int g = 0; g < 4; ++g) {
        int kc = kt * 64 + g * 16 + lrow;
#pragma unroll
        for (int i = 0; i < 4; ++i) {
          int qr = q0 + (lane >> 4) * 4 + i;
          if (kc > qr) s[g][i] = -1e30f;
        }
      }
    }
    float mnew[4], scl[4], rs[4];
#pragma unroll
    for (int i = 0; i < 4; ++i) {
      float pm = fmaxf(fmaxf(s[0][i], s[1][i]), fmaxf(s[2][i], s[3][i]));
      pm = fmaxf(pm, __shfl_xor(pm, 1));
      pm = fmaxf(pm, __shfl_xor(pm, 2));
      pm = fmaxf(pm, __shfl_xor(pm, 4));
      pm = fmaxf(pm, __shfl_xor(pm, 8));
      mnew[i] = fmaxf(m_i[i], pm);
      scl[i] = __expf(m_i[i] - mnew[i]);
      rs[i] = 0.f;
    }
#pragma unroll
    for (int g = 0; g < 4; ++g)
#pragma unroll
      for (int i = 0; i < 4; ++i) {
        float p = __expf(s[g][i] - mnew[i]);
        s[g][i] = p;
        rs[i] += p;
      }
#pragma unroll
    for (int i = 0; i < 4; ++i) {
      rs[i] += __shfl_xor(rs[i], 1);
      rs[i] += __shfl_xor(rs[i], 2);
      rs[i] += __shfl_xor(rs[i], 4);
      rs[i] += __shfl_xor(rs[i], 8);
      l_i[i] = l_i[i] * scl[i] + rs[i];
      m_i[i] = mnew[i];
    }
#pragma unroll
    for (int g = 0; g < 4; ++g) {
      hacc[g][0] *= scl[0]; hacc[g][1] *= scl[1];
      hacc[g][2] *= scl[2]; hacc[g][3] *= scl[3];
    }
    // P -> LDS (per-wave tile) to reach MFMA A-fragment layout
#pragma unroll
    for (int g = 0; g < 4; ++g)
#pragma unroll
      for (int i = 0; i < 4; ++i)
        Ps[w][((lane >> 4) * 4 + i) * 64 + g * 16 + (lane & 15)] = f2bf(s[g][i]);
    __syncthreads();
#pragma unroll
    for (int ks = 0; ks < 2; ++ks) {
      bf16x8 pf = *(const bf16x8*)(&Ps[w][lrow * 64 + ks * 32 + lk8]);
#pragma unroll
      for (int g = 0; g < 4; ++g) {
        bf16x8 vf = *(const bf16x8*)(Vp + (size_t)(g * 16 + lrow) * SEQ + kt * 64 + ks * 32 + lk8);
        hacc[g] = __builtin_amdgcn_mfma_f32_16x16x32_bf16(pf, vf, hacc[g], 0, 0, 0);
      }
    }
    __syncthreads();
  }

  const int b = bh >> 4, h = bh & 15;
#pragma unroll
  for (int i = 0; i < 4; ++i) {
    float inv = 1.0f / l_i[i];
    int srow = q0 + (lane >> 4) * 4 + i;
#pragma unroll
    for (int g = 0; g < 4; ++g) {
      int d = g * 16 + (lane & 15);
      Hh[((size_t)b * SEQ + srow) * DM + h * DH + d] = f2bf(hacc[g][i] * inv);
    }
  }
}

extern "C" void kernel_launch(void* const* d_in, const int* in_sizes, int n_in,
                              void* d_out, int out_size, void* d_ws, size_t ws_size,
                              hipStream_t stream) {
  const float* x  = (const float*)d_in[0];
  const float* Wq = (const float*)d_in[1];
  const float* bq = (const float*)d_in[2];
  const float* Wk = (const float*)d_in[3];
  const float* bk = (const float*)d_in[4];
  const float* Wv = (const float*)d_in[5];
  const float* bv = (const float*)d_in[6];
  const float* Wo = (const float*)d_in[7];
  const float* bo = (const float*)d_in[8];
  float* out = (float*)d_out;

  // workspace layout (bytes): total 48 MiB
  char* ws = (char*)d_ws;
  u16* Xb  = (u16*)(ws);                    // 8 MiB  [4096,1024] bf16
  u16* Wt  = (u16*)(ws + (8u << 20));       // 8 MiB  4x [1024,1024] bf16 (transposed)
  u16* Qb  = (u16*)(ws + (16u << 20));      // 8 MiB  [B,H,S,DH]
  u16* Kb  = (u16*)(ws + (24u << 20));      // 8 MiB  [B,H,S,DH]
  u16* Vt  = (u16*)(ws + (32u << 20));      // 8 MiB  [B,H,DH,S]
  u16* Hh  = (u16*)(ws + (40u << 20));      // 8 MiB  [B,S,DM]
  (void)in_sizes; (void)n_in; (void)out_size; (void)ws_size;

  // 1) convert x
  cvt_kernel<<<4096, 256, 0, stream>>>(x, Xb, 4096 * 1024 / 4);
  // 2) transpose+convert weights
  dim3 tg(32, 32);
  wtrans_kernel<<<tg, 256, 0, stream>>>(Wq, Wt);
  wtrans_kernel<<<tg, 256, 0, stream>>>(Wk, Wt + (1u << 20));
  wtrans_kernel<<<tg, 256, 0, stream>>>(Wv, Wt + (2u << 20));
  wtrans_kernel<<<tg, 256, 0, stream>>>(Wo, Wt + (3u << 20));
  // 3) fused QKV projection
  dim3 gq(8, 32, 3);
  gemm_kernel<<<gq, 256, 0, stream>>>(Xb, Wt, bq, bk, bv, Qb, Kb, Vt, 0);
  // 4) causal flash attention -> Hh [B,S,DM] bf16
  dim3 ga(32, 32);
  attn_kernel<<<ga, 256, 0, stream>>>(Qb, Kb, Vt, Hh);
  // 5) output projection -> fp32 d_out
  dim3 go(8, 32, 1);
  gemm_kernel<<<go, 256, 0, stream>>>(Hh, Wt + (3u << 20), bo, bo, bo, out, out, out, 3);
}

// Round 2
// 240.467 us; speedup vs baseline: 2.0933x; 2.0933x over previous
//
#include <hip/hip_runtime.h>

typedef unsigned short u16;
typedef __attribute__((ext_vector_type(8))) __bf16 bf16x8;
typedef __attribute__((ext_vector_type(4))) float f32x4;
typedef __attribute__((ext_vector_type(4))) unsigned short u16x4;

#define SEQ 2048
#define DM 1024
#define NH 16
#define DH 64
// M = BATCH*SEQ = 4096, N = 1024, K = 1024 for all GEMMs

__device__ __forceinline__ unsigned short f2bf(float f) {
  unsigned u = __builtin_bit_cast(unsigned, f);
  u += 0x7fffu + ((u >> 16) & 1u);
  return (unsigned short)(u >> 16);
}

__device__ __forceinline__ void gload_lds16(const u16* g, u16* l) {
  __builtin_amdgcn_global_load_lds(
      (const __attribute__((address_space(1))) u16*)g,
      (__attribute__((address_space(3))) u16*)l, 16, 0, 0);
}

// ---------- convert x fp32 -> bf16 ----------
__global__ __launch_bounds__(256) void cvt_kernel(const float* __restrict__ in,
                                                  u16* __restrict__ out, int n4) {
  int id = blockIdx.x * 256 + threadIdx.x;
  if (id >= n4) return;
  float4 v = ((const float4*)in)[id];
  u16x4 o = { f2bf(v.x), f2bf(v.y), f2bf(v.z), f2bf(v.w) };
  ((u16x4*)out)[id] = o;
}

// ---------- transpose + convert weight: Wt[n][k] = W[k][n] ----------
__global__ __launch_bounds__(256) void wtrans_kernel(const float* __restrict__ W,
                                                     u16* __restrict__ Wt) {
  __shared__ float tile[32][33];
  int tx = threadIdx.x & 31, ty = threadIdx.x >> 5; // 32 x 8
  int k0 = blockIdx.y * 32, n0 = blockIdx.x * 32;
#pragma unroll
  for (int j = 0; j < 32; j += 8)
    tile[ty + j][tx] = W[(size_t)(k0 + ty + j) * DM + n0 + tx];
  __syncthreads();
#pragma unroll
  for (int j = 0; j < 32; j += 8)
    Wt[(size_t)(n0 + ty + j) * DM + k0 + tx] = f2bf(tile[tx][ty + j]);
}

// ---------- GEMM: C = A(bf16 [4096,1024]) @ Wt^T + bias ----------
// modes: 0=Q  -> [B,H,S,DH] bf16, scaled by 0.125 (1/sqrt(DH))
//        1=K  -> [B,H,S,DH] bf16
//        2=V  -> [B,H,DH,S] bf16 (transposed for PV B-fragments)
//        3=O  -> [4096,1024] fp32 (final output)
__global__ __launch_bounds__(256) void gemm_kernel(
    const u16* __restrict__ A, const u16* __restrict__ WtBase,
    const float* __restrict__ b0, const float* __restrict__ b1,
    const float* __restrict__ b2,
    void* __restrict__ O0, void* __restrict__ O1, void* __restrict__ O2,
    int modeBase) {
  const int Kd = 1024, Nd = 1024;
  const int mode = modeBase + blockIdx.z;
  const u16* Bt = WtBase + (size_t)blockIdx.z * (1u << 20);
  const float* bias = (blockIdx.z == 0) ? b0 : (blockIdx.z == 1) ? b1 : b2;
  void* Out = (blockIdx.z == 0) ? O0 : (blockIdx.z == 1) ? O1 : O2;

  __shared__ u16 As[128 * 32];
  __shared__ u16 Bs[128 * 32];
  const int tid = threadIdx.x;
  const int lane = tid & 63, w = tid >> 6;
  const int wr = w >> 1, wc = w & 1;
  const int brow = blockIdx.y * 128, bcol = blockIdx.x * 128;

  f32x4 acc[4][4] = {};

  const int srow = tid >> 2;        // 0..63, includes wave bits
  const int scol = (tid & 3) * 8;
  const u16* a0 = A + (size_t)(brow + srow) * Kd + scol;
  const u16* a1 = A + (size_t)(brow + 64 + srow) * Kd + scol;
  const u16* bt0 = Bt + (size_t)(bcol + srow) * Kd + scol;
  const u16* bt1 = Bt + (size_t)(bcol + 64 + srow) * Kd + scol;
  u16* asl = As + w * 512; // wave-uniform LDS base; +2048 for issue 1
  u16* bsl = Bs + w * 512;

  for (int kt = 0; kt < Kd; kt += 32) {
    gload_lds16(a0 + kt, asl);
    gload_lds16(a1 + kt, asl + 2048);
    gload_lds16(bt0 + kt, bsl);
    gload_lds16(bt1 + kt, bsl + 2048);
    __syncthreads();
    bf16x8 af[4], bfr[4];
#pragma unroll
    for (int m = 0; m < 4; ++m)
      af[m] = *(const bf16x8*)(As + (wr * 64 + m * 16 + (lane & 15)) * 32 + (lane >> 4) * 8);
#pragma unroll
    for (int n = 0; n < 4; ++n)
      bfr[n] = *(const bf16x8*)(Bs + (wc * 64 + n * 16 + (lane & 15)) * 32 + (lane >> 4) * 8);
#pragma unroll
    for (int m = 0; m < 4; ++m)
#pragma unroll
      for (int n = 0; n < 4; ++n)
        acc[m][n] = __builtin_amdgcn_mfma_f32_16x16x32_bf16(af[m], bfr[n], acc[m][n], 0, 0, 0);
    __syncthreads();
  }

  const int r0 = brow + wr * 64 + (lane >> 4) * 4; // + m*16 + i
  const int c0 = bcol + wc * 64 + (lane & 15);     // + n*16
#pragma unroll
  for (int m = 0; m < 4; ++m) {
#pragma unroll
    for (int n = 0; n < 4; ++n) {
      const int col = c0 + n * 16;
      const float bv = bias[col];
      if (mode == 3) {
        float* O = (float*)Out;
#pragma unroll
        for (int i = 0; i < 4; ++i) {
          int row = r0 + m * 16 + i;
          O[(size_t)row * Nd + col] = acc[m][n][i] + bv;
        }
      } else if (mode == 2) {
        // V transposed: Vt[((b*16+h)*64+dh)*2048 + s], 4 consecutive s per thread
        const int rowb = r0 + m * 16;
        const int b = rowb >> 11, s = rowb & 2047;
        const int h = col >> 6, dh = col & 63;
        u16x4 pk;
#pragma unroll
        for (int i = 0; i < 4; ++i) pk[i] = f2bf(acc[m][n][i] + bv);
        u16* O = (u16*)Out;
        *(u16x4*)(O + ((size_t)((b * NH + h) * DH + dh) * SEQ + s)) = pk;
      } else {
        const float sc = (mode == 0) ? 0.125f : 1.0f;
        u16* O = (u16*)Out;
#pragma unroll
        for (int i = 0; i < 4; ++i) {
          int row = r0 + m * 16 + i;
          int b = row >> 11, s = row & 2047;
          int h = col >> 6, dh = col & 63;
          O[((size_t)(b * NH + h) * SEQ + s) * DH + dh] = f2bf((acc[m][n][i] + bv) * sc);
        }
      }
    }
  }
}

// ---------- causal flash attention, v2 ----------
// grid: (16 qpairs, 32 bh). Block = 256 threads = 4 waves.
// Block px handles q-tiles qtA=px and qtB=31-px (uniform 33 compute-iters).
// K/V tiles (64x64 bf16 each) cooperatively staged into LDS via
// global_load_lds (pre-swizzled source, XOR (row&7)<<4), double-buffered.
__device__ __forceinline__ void process_tile(
    const u16* bufK, const u16* bufV, u16* ps,
    bf16x8 (&qf)[2], f32x4 (&hacc)[4], float (&m_i)[4], float (&l_i)[4],
    int lane, int w, bool diag) {
  const int lrow = lane & 15;
  const int lk16 = (lane >> 4) * 16; // byte col base within 128B row

  f32x4 s[4] = {};
#pragma unroll
  for (int ks = 0; ks < 2; ++ks) {
    const int c = ks * 64 + lk16;
#pragma unroll
    for (int g = 0; g < 4; ++g) {
      const int r = g * 16 + lrow;
      const bf16x8 kf = *(const bf16x8*)(bufK + ((r * 128 + (c ^ ((r & 7) << 4))) >> 1));
      s[g] = __builtin_amdgcn_mfma_f32_16x16x32_bf16(qf[ks], kf, s[g], 0, 0, 0);
    }
  }
  if (diag) {
#pragma unroll
    for (int g = 0; g < 4; ++g) {
      const int kc = g * 16 + lrow;
#pragma unroll
      for (int i = 0; i < 4; ++i) {
        const int qr = w * 16 + (lane >> 4) * 4 + i;
        if (kc > qr) s[g][i] = -1e30f;
      }
    }
  }
  float mnew[4], scl[4], rs[4];
#pragma unroll
  for (int i = 0; i < 4; ++i) {
    float pm = fmaxf(fmaxf(s[0][i], s[1][i]), fmaxf(s[2][i], s[3][i]));
    pm = fmaxf(pm, __shfl_xor(pm, 1));
    pm = fmaxf(pm, __shfl_xor(pm, 2));
    pm = fmaxf(pm, __shfl_xor(pm, 4));
    pm = fmaxf(pm, __shfl_xor(pm, 8));
    mnew[i] = fmaxf(m_i[i], pm);
    scl[i] = __expf(m_i[i] - mnew[i]);
    rs[i] = 0.f;
  }
#pragma unroll
  for (int g = 0; g < 4; ++g)
#pragma unroll
    for (int i = 0; i < 4; ++i) {
      float p = __expf(s[g][i] - mnew[i]);
      s[g][i] = p;
      rs[i] += p;
    }
#pragma unroll
  for (int i = 0; i < 4; ++i) {
    rs[i] += __shfl_xor(rs[i], 1);
    rs[i] += __shfl_xor(rs[i], 2);
    rs[i] += __shfl_xor(rs[i], 4);
    rs[i] += __shfl_xor(rs[i], 8);
    l_i[i] = l_i[i] * scl[i] + rs[i];
    m_i[i] = mnew[i];
  }
#pragma unroll
  for (int g = 0; g < 4; ++g) {
    hacc[g][0] *= scl[0]; hacc[g][1] *= scl[1];
    hacc[g][2] *= scl[2]; hacc[g][3] *= scl[3];
  }
  // P -> per-wave LDS tile (swizzled), no block barrier needed
#pragma unroll
  for (int g = 0; g < 4; ++g)
#pragma unroll
    for (int i = 0; i < 4; ++i) {
      const int r = (lane >> 4) * 4 + i;
      const int cb = (g * 16 + (lane & 15)) * 2;
      ps[(r * 128 + (cb ^ ((r & 7) << 4))) >> 1] = f2bf(s[g][i]);
    }
#pragma unroll
  for (int ks = 0; ks < 2; ++ks) {
    const int c = ks * 64 + lk16;
    const bf16x8 pf = *(const bf16x8*)(ps + ((lrow * 128 + (c ^ ((lrow & 7) << 4))) >> 1));
#pragma unroll
    for (int g = 0; g < 4; ++g) {
      const int r = g * 16 + lrow;
      const bf16x8 vf = *(const bf16x8*)(bufV + ((r * 128 + (c ^ ((r & 7) << 4))) >> 1));
      hacc[g] = __builtin_amdgcn_mfma_f32_16x16x32_bf16(pf, vf, hacc[g], 0, 0, 0);
    }
  }
}

__global__ __launch_bounds__(256, 2) void attn_kernel(const u16* __restrict__ Qb,
                                                      const u16* __restrict__ Kb,
                                                      const u16* __restrict__ Vt,
                                                      u16* __restrict__ Hh) {
  const int px = blockIdx.x, bh = blockIdx.y;
  const int qtA = px, qtB = 31 - px;
  const int tid = threadIdx.x, lane = tid & 63, w = tid >> 6;
  const int lrow = lane & 15, lk8 = (lane >> 4) * 8;

  const u16* Qp = Qb + (size_t)bh * SEQ * DH;
  const u16* Kp = Kb + (size_t)bh * SEQ * DH;
  const u16* Vp = Vt + (size_t)bh * DH * SEQ;

  __shared__ u16 KV[2][2][4096]; // [buf][K=0/V=1][64 rows x 64 cols], swizzled
  __shared__ u16 Ps[4][1024];    // per-wave P tile [16][64], swizzled

  const int q0A = qtA * 64 + w * 16, q0B = qtB * 64 + w * 16;
  bf16x8 qfA[2], qfB[2];
#pragma unroll
  for (int ks = 0; ks < 2; ++ks) {
    qfA[ks] = *(const bf16x8*)(Qp + (size_t)(q0A + lrow) * DH + ks * 32 + lk8);
    qfB[ks] = *(const bf16x8*)(Qp + (size_t)(q0B + lrow) * DH + ks * 32 + lk8);
  }

  float mA[4], lA[4], mB[4], lB[4];
  f32x4 haccA[4], haccB[4];
#pragma unroll
  for (int i = 0; i < 4; ++i) { mA[i] = -1e30f; lA[i] = 0.f; mB[i] = -1e30f; lB[i] = 0.f; }
#pragma unroll
  for (int g = 0; g < 4; ++g) {
    haccA[g] = (f32x4){0.f, 0.f, 0.f, 0.f};
    haccB[g] = (f32x4){0.f, 0.f, 0.f, 0.f};
  }

  // cooperative tile stage: 256 thr x 16B x 2 issues per 8KB tile
  auto stage = [&](int kt, int buf) {
#pragma unroll
    for (int i = 0; i < 2; ++i) {
      const int p = i * 4096 + tid * 16;      // linear phys byte in tile
      const int row = p >> 7;                 // 128B rows
      const int c16 = ((p >> 4) & 7) ^ (row & 7); // pre-swizzled source col (16B units)
      gload_lds16(Kp + (size_t)(kt * 64 + row) * 64 + c16 * 8, &KV[buf][0][p >> 1]);
      gload_lds16(Vp + (size_t)row * 2048 + (size_t)kt * 64 + c16 * 8, &KV[buf][1][p >> 1]);
    }
  };

  stage(0, 0);
  __syncthreads();

  const int nkt = qtB + 1;
  for (int kt = 0; kt < nkt; ++kt) {
    const int cur = kt & 1;
    if (kt + 1 < nkt) stage(kt + 1, cur ^ 1); // prefetch overlaps compute
    if (kt <= qtA)
      process_tile(KV[cur][0], KV[cur][1], Ps[w], qfA, haccA, mA, lA, lane, w, kt == qtA);
    process_tile(KV[cur][0], KV[cur][1], Ps[w], qfB, haccB, mB, lB, lane, w, kt == qtB);
    __syncthreads(); // prefetch landed + everyone done with cur
  }

  const int b = bh >> 4, h = bh & 15;
#pragma unroll
  for (int i = 0; i < 4; ++i) {
    const float invA = 1.0f / lA[i], invB = 1.0f / lB[i];
    const int srA = q0A + (lane >> 4) * 4 + i;
    const int srB = q0B + (lane >> 4) * 4 + i;
#pragma unroll
    for (int g = 0; g < 4; ++g) {
      const int d = g * 16 + (lane & 15);
      Hh[((size_t)b * SEQ + srA) * DM + h * DH + d] = f2bf(haccA[g][i] * invA);
      Hh[((size_t)b * SEQ + srB) * DM + h * DH + d] = f2bf(haccB[g][i] * invB);
    }
  }
}

extern "C" void kernel_launch(void* const* d_in, const int* in_sizes, int n_in,
                              void* d_out, int out_size, void* d_ws, size_t ws_size,
                              hipStream_t stream) {
  const float* x  = (const float*)d_in[0];
  const float* Wq = (const float*)d_in[1];
  const float* bq = (const float*)d_in[2];
  const float* Wk = (const float*)d_in[3];
  const float* bk = (const float*)d_in[4];
  const float* Wv = (const float*)d_in[5];
  const float* bv = (const float*)d_in[6];
  const float* Wo = (const float*)d_in[7];
  const float* bo = (const float*)d_in[8];
  float* out = (float*)d_out;

  // workspace layout (bytes): total 48 MiB
  char* ws = (char*)d_ws;
  u16* Xb  = (u16*)(ws);                    // 8 MiB  [4096,1024] bf16
  u16* Wt  = (u16*)(ws + (8u << 20));       // 8 MiB  4x [1024,1024] bf16 (transposed)
  u16* Qb  = (u16*)(ws + (16u << 20));      // 8 MiB  [B,H,S,DH]
  u16* Kb  = (u16*)(ws + (24u << 20));      // 8 MiB  [B,H,S,DH]
  u16* Vt  = (u16*)(ws + (32u << 20));      // 8 MiB  [B,H,DH,S]
  u16* Hh  = (u16*)(ws + (40u << 20));      // 8 MiB  [B,S,DM]
  (void)in_sizes; (void)n_in; (void)out_size; (void)ws_size;

  // 1) convert x
  cvt_kernel<<<4096, 256, 0, stream>>>(x, Xb, 4096 * 1024 / 4);
  // 2) transpose+convert weights
  dim3 tg(32, 32);
  wtrans_kernel<<<tg, 256, 0, stream>>>(Wq, Wt);
  wtrans_kernel<<<tg, 256, 0, stream>>>(Wk, Wt + (1u << 20));
  wtrans_kernel<<<tg, 256, 0, stream>>>(Wv, Wt + (2u << 20));
  wtrans_kernel<<<tg, 256, 0, stream>>>(Wo, Wt + (3u << 20));
  // 3) fused QKV projection
  dim3 gq(8, 32, 3);
  gemm_kernel<<<gq, 256, 0, stream>>>(Xb, Wt, bq, bk, bv, Qb, Kb, Vt, 0);
  // 4) causal flash attention -> Hh [B,S,DM] bf16
  dim3 ga(16, 32);
  attn_kernel<<<ga, 256, 0, stream>>>(Qb, Kb, Vt, Hh);
  // 5) output projection -> fp32 d_out
  dim3 go(8, 32, 1);
  gemm_kernel<<<go, 256, 0, stream>>>(Hh, Wt + (3u << 20), bo, bo, bo, out, out, out, 3);
}

// Round 4
// 204.278 us; speedup vs baseline: 2.4642x; 1.1772x over previous
//
#include <hip/hip_runtime.h>

typedef unsigned short u16;
typedef unsigned int u32;
typedef __attribute__((ext_vector_type(8))) __bf16 bf16x8;
typedef __attribute__((ext_vector_type(4))) float f32x4;
typedef __attribute__((ext_vector_type(4))) unsigned short u16x4;

#define SEQ 2048
#define DM 1024
#define NH 16
#define DH 64
// M = BATCH*SEQ = 4096, N = 1024, K = 1024 for all GEMMs

__device__ __forceinline__ float fexp2(float x) {
  return __builtin_amdgcn_exp2f(x); // raw v_exp_f32 (2^x)
}

__device__ __forceinline__ unsigned short f2bf(float f) {
  unsigned u = __builtin_bit_cast(unsigned, f);
  u += 0x7fffu + ((u >> 16) & 1u);
  return (unsigned short)(u >> 16);
}

__device__ __forceinline__ void gload_lds16(const u16* g, u16* l) {
  __builtin_amdgcn_global_load_lds(
      (const __attribute__((address_space(1))) u16*)g,
      (__attribute__((address_space(3))) u16*)l, 16, 0, 0);
}

// ---------- convert x fp32 -> bf16 ----------
__global__ __launch_bounds__(256) void cvt_kernel(const float* __restrict__ in,
                                                  u16* __restrict__ out, int n4) {
  int id = blockIdx.x * 256 + threadIdx.x;
  if (id >= n4) return;
  float4 v = ((const float4*)in)[id];
  u16x4 o = { f2bf(v.x), f2bf(v.y), f2bf(v.z), f2bf(v.w) };
  ((u16x4*)out)[id] = o;
}

// ---------- transpose + convert weights (all 4 in one launch, z selects) ----
__global__ __launch_bounds__(256) void wtrans_kernel(const float* __restrict__ W0,
                                                     const float* __restrict__ W1,
                                                     const float* __restrict__ W2,
                                                     const float* __restrict__ W3,
                                                     u16* __restrict__ WtBase) {
  const float* W = (blockIdx.z == 0) ? W0 : (blockIdx.z == 1) ? W1
                 : (blockIdx.z == 2) ? W2 : W3;
  u16* Wt = WtBase + ((size_t)blockIdx.z << 20);
  __shared__ float tile[32][33];
  int tx = threadIdx.x & 31, ty = threadIdx.x >> 5; // 32 x 8
  int k0 = blockIdx.y * 32, n0 = blockIdx.x * 32;
#pragma unroll
  for (int j = 0; j < 32; j += 8)
    tile[ty + j][tx] = W[(size_t)(k0 + ty + j) * DM + n0 + tx];
  __syncthreads();
#pragma unroll
  for (int j = 0; j < 32; j += 8)
    Wt[(size_t)(n0 + ty + j) * DM + k0 + tx] = f2bf(tile[tx][ty + j]);
}

// ---------- GEMM: C = A(bf16 [4096,1024]) @ Wt^T + bias ----------
// modes: 0=Q  -> [B,H,S,DH] bf16, scaled by 0.125*log2(e) (softmax in exp2)
//        1=K  -> [B,H,S,DH] bf16
//        2=V  -> [B,H,DH,S] bf16 (transposed for PV A-fragments)
//        3=O  -> [4096,1024] fp32 (final output)
__global__ __launch_bounds__(256) void gemm_kernel(
    const u16* __restrict__ A, const u16* __restrict__ WtBase,
    const float* __restrict__ b0, const float* __restrict__ b1,
    const float* __restrict__ b2,
    void* __restrict__ O0, void* __restrict__ O1, void* __restrict__ O2,
    int modeBase) {
  const int Kd = 1024, Nd = 1024;
  const int mode = modeBase + blockIdx.z;
  const u16* Bt = WtBase + (size_t)blockIdx.z * (1u << 20);
  const float* bias = (blockIdx.z == 0) ? b0 : (blockIdx.z == 1) ? b1 : b2;
  void* Out = (blockIdx.z == 0) ? O0 : (blockIdx.z == 1) ? O1 : O2;

  __shared__ u16 As[2][4096]; // [buf][128 rows x 32 cols]
  __shared__ u16 Bs[2][4096];
  const int tid = threadIdx.x;
  const int lane = tid & 63, w = tid >> 6;
  const int lrow = lane & 15, u = lane >> 4;
  const int wr = w >> 1, wc = w & 1;
  const int brow = blockIdx.y * 128, bcol = blockIdx.x * 128;

  f32x4 acc[4][4] = {};

  const int srow = tid >> 2;        // 0..63, includes wave bits
  const int scol = (tid & 3) * 8;
  const u16* a0 = A + (size_t)(brow + srow) * Kd + scol;
  const u16* a1 = A + (size_t)(brow + 64 + srow) * Kd + scol;
  const u16* bt0 = Bt + (size_t)(bcol + srow) * Kd + scol;
  const u16* bt1 = Bt + (size_t)(bcol + 64 + srow) * Kd + scol;

  auto stage = [&](int kt, int buf) {
    gload_lds16(a0 + kt, As[buf] + w * 512);
    gload_lds16(a1 + kt, As[buf] + 2048 + w * 512);
    gload_lds16(bt0 + kt, Bs[buf] + w * 512);
    gload_lds16(bt1 + kt, Bs[buf] + 2048 + w * 512);
  };

  stage(0, 0);
  __syncthreads();

  for (int it = 0; it < 32; ++it) {
    const int cur = it & 1;
    if (it + 1 < 32) stage((it + 1) * 32, cur ^ 1); // prefetch overlaps compute
    bf16x8 af[4], bfr[4];
#pragma unroll
    for (int m = 0; m < 4; ++m)
      af[m] = *(const bf16x8*)(As[cur] + (wr * 64 + m * 16 + lrow) * 32 + u * 8);
#pragma unroll
    for (int n = 0; n < 4; ++n)
      bfr[n] = *(const bf16x8*)(Bs[cur] + (wc * 64 + n * 16 + lrow) * 32 + u * 8);
#pragma unroll
    for (int m = 0; m < 4; ++m)
#pragma unroll
      for (int n = 0; n < 4; ++n)
        acc[m][n] = __builtin_amdgcn_mfma_f32_16x16x32_bf16(af[m], bfr[n], acc[m][n], 0, 0, 0);
    __syncthreads();
  }

  const int r0 = brow + wr * 64 + u * 4; // + m*16 + i
  const int c0 = bcol + wc * 64 + lrow;  // + n*16
#pragma unroll
  for (int m = 0; m < 4; ++m) {
#pragma unroll
    for (int n = 0; n < 4; ++n) {
      const int col = c0 + n * 16;
      const float bv = bias[col];
      if (mode == 3) {
        float* O = (float*)Out;
#pragma unroll
        for (int i = 0; i < 4; ++i) {
          int row = r0 + m * 16 + i;
          O[(size_t)row * Nd + col] = acc[m][n][i] + bv;
        }
      } else if (mode == 2) {
        // V transposed: Vt[((b*16+h)*64+dh)*2048 + s], 4 consecutive s per thread
        const int rowb = r0 + m * 16;
        const int b = rowb >> 11, s = rowb & 2047;
        const int h = col >> 6, dh = col & 63;
        u16x4 pk;
#pragma unroll
        for (int i = 0; i < 4; ++i) pk[i] = f2bf(acc[m][n][i] + bv);
        u16* O = (u16*)Out;
        *(u16x4*)(O + ((size_t)((b * NH + h) * DH + dh) * SEQ + s)) = pk;
      } else {
        const float sc = (mode == 0) ? 0.1803368801111204f : 1.0f; // 0.125*log2e
        u16* O = (u16*)Out;
#pragma unroll
        for (int i = 0; i < 4; ++i) {
          int row = r0 + m * 16 + i;
          int b = row >> 11, s = row & 2047;
          int h = col >> 6, dh = col & 63;
          O[((size_t)(b * NH + h) * SEQ + s) * DH + dh] = f2bf((acc[m][n][i] + bv) * sc);
        }
      }
    }
  }
}

// ---------- causal flash attention, v3 (swapped QK^T) ----------
// grid: (16 qpairs, 32 bh). Block = 256 threads = 4 waves.
// Swapped layout: mfma(K,Q) -> lane owns ONE q-row (q=lane&15), k in-lane.
// Softmax: in-lane tree + 2 shuffles. P stored row-major [q][k] as packed u32.
// PV: H^T = mfma(V^T, P^T): Vt tile rows are A-fragments, P rows are B-frags.
__device__ __forceinline__ void process_tile(
    const u16* bufK, const u16* bufV, u16* ps,
    const bf16x8 (&qf)[2], f32x4 (&hacc)[4], float& m_i, float& l_i,
    int lrow, int u, int wq, bool diag) {
  f32x4 s[4] = {};
#pragma unroll
  for (int ks = 0; ks < 2; ++ks) {
    const int c = ks * 64 + u * 16; // byte col within 128B row
#pragma unroll
    for (int g = 0; g < 4; ++g) {
      const int r = g * 16 + lrow;
      const bf16x8 kf = *(const bf16x8*)(bufK + ((r * 128 + (c ^ ((r & 7) << 4))) >> 1));
      s[g] = __builtin_amdgcn_mfma_f32_16x16x32_bf16(kf, qf[ks], s[g], 0, 0, 0);
    }
  }
  // s[g][i] = S[k = g*16+u*4+i][q = lrow]  (log2-domain scores)
  if (diag) {
#pragma unroll
    for (int g = 0; g < 4; ++g) {
      const int kb = g * 16 + u * 4;
#pragma unroll
      for (int i = 0; i < 4; ++i)
        if (kb + i > wq) s[g][i] = -1e30f;
    }
  }
  float pg[4];
#pragma unroll
  for (int g = 0; g < 4; ++g)
    pg[g] = fmaxf(fmaxf(s[g][0], s[g][1]), fmaxf(s[g][2], s[g][3]));
  float pmax = fmaxf(fmaxf(pg[0], pg[1]), fmaxf(pg[2], pg[3]));
  pmax = fmaxf(pmax, __shfl_xor(pmax, 16));
  pmax = fmaxf(pmax, __shfl_xor(pmax, 32));
  const float mnew = fmaxf(m_i, pmax);
  const float scl = fexp2(m_i - mnew);
  float rs = 0.f;
#pragma unroll
  for (int g = 0; g < 4; ++g)
#pragma unroll
    for (int i = 0; i < 4; ++i) {
      const float p = fexp2(s[g][i] - mnew);
      s[g][i] = p;
      rs += p;
    }
  rs += __shfl_xor(rs, 16);
  rs += __shfl_xor(rs, 32);
  l_i = l_i * scl + rs;
  m_i = mnew;
#pragma unroll
  for (int g = 0; g < 4; ++g) hacc[g] *= scl;
  // P[q=lrow][k] row-major, packed u32 (2 bf16), swizzled like K/V tiles
#pragma unroll
  for (int g = 0; g < 4; ++g)
#pragma unroll
    for (int h = 0; h < 2; ++h) {
      const u32 w32 = (u32)f2bf(s[g][2 * h]) | ((u32)f2bf(s[g][2 * h + 1]) << 16);
      const int cb = (g * 16 + u * 4 + 2 * h) * 2; // byte col
      *(u32*)(ps + ((lrow * 128 + (cb ^ ((lrow & 7) << 4))) >> 1)) = w32;
    }
  // PV: hacc[g] = H^T tile (rows d = g*16+u*4+i, col q = lrow)
#pragma unroll
  for (int ks = 0; ks < 2; ++ks) {
    const int c = ks * 64 + u * 16;
    const bf16x8 pf = *(const bf16x8*)(ps + ((lrow * 128 + (c ^ ((lrow & 7) << 4))) >> 1));
#pragma unroll
    for (int g = 0; g < 4; ++g) {
      const int r = g * 16 + lrow;
      const bf16x8 vf = *(const bf16x8*)(bufV + ((r * 128 + (c ^ ((r & 7) << 4))) >> 1));
      hacc[g] = __builtin_amdgcn_mfma_f32_16x16x32_bf16(vf, pf, hacc[g], 0, 0, 0);
    }
  }
}

__global__ __launch_bounds__(256, 2) void attn_kernel(const u16* __restrict__ Qb,
                                                      const u16* __restrict__ Kb,
                                                      const u16* __restrict__ Vt,
                                                      u16* __restrict__ Hh) {
  const int px = blockIdx.x, bh = blockIdx.y;
  const int qtA = px, qtB = 31 - px;
  const int tid = threadIdx.x, lane = tid & 63, w = tid >> 6;
  const int lrow = lane & 15, u = lane >> 4;

  const u16* Qp = Qb + (size_t)bh * SEQ * DH;
  const u16* Kp = Kb + (size_t)bh * SEQ * DH;
  const u16* Vp = Vt + (size_t)bh * DH * SEQ;

  __shared__ u16 KV[2][2][4096]; // [buf][K=0/V=1][64 rows x 64 cols], swizzled
  __shared__ u16 Ps[4][1024];    // per-wave P tile [16][64], swizzled

  const int q0A = qtA * 64 + w * 16, q0B = qtB * 64 + w * 16;
  bf16x8 qfA[2], qfB[2];
#pragma unroll
  for (int ks = 0; ks < 2; ++ks) {
    qfA[ks] = *(const bf16x8*)(Qp + (size_t)(q0A + lrow) * DH + ks * 32 + u * 8);
    qfB[ks] = *(const bf16x8*)(Qp + (size_t)(q0B + lrow) * DH + ks * 32 + u * 8);
  }

  float mA = -1e30f, lA = 0.f, mB = -1e30f, lB = 0.f;
  f32x4 haccA[4], haccB[4];
#pragma unroll
  for (int g = 0; g < 4; ++g) {
    haccA[g] = (f32x4){0.f, 0.f, 0.f, 0.f};
    haccB[g] = (f32x4){0.f, 0.f, 0.f, 0.f};
  }

  // cooperative tile stage: 256 thr x 16B x 2 issues per 8KB tile
  auto stage = [&](int kt, int buf) {
#pragma unroll
    for (int i = 0; i < 2; ++i) {
      const int p = i * 4096 + tid * 16;          // linear phys byte in tile
      const int row = p >> 7;                     // 128B rows
      const int c16 = ((p >> 4) & 7) ^ (row & 7); // pre-swizzled source col (16B units)
      gload_lds16(Kp + (size_t)(kt * 64 + row) * 64 + c16 * 8, &KV[buf][0][p >> 1]);
      gload_lds16(Vp + (size_t)row * 2048 + (size_t)kt * 64 + c16 * 8, &KV[buf][1][p >> 1]);
    }
  };

  stage(0, 0);
  __syncthreads();

  const int wq = w * 16 + lrow;
  const int nkt = qtB + 1;
  for (int kt = 0; kt < nkt; ++kt) {
    const int cur = kt & 1;
    if (kt + 1 < nkt) stage(kt + 1, cur ^ 1); // prefetch overlaps compute
    if (kt <= qtA)
      process_tile(KV[cur][0], KV[cur][1], Ps[w], qfA, haccA, mA, lA, lrow, u, wq, kt == qtA);
    process_tile(KV[cur][0], KV[cur][1], Ps[w], qfB, haccB, mB, lB, lrow, u, wq, kt == qtB);
    __syncthreads(); // prefetch landed + everyone done with cur
  }

  const int b = bh >> 4, h = bh & 15;
  {
    const float inv = 1.0f / lA;
    u16* dst = Hh + ((size_t)b * SEQ + (q0A + lrow)) * DM + h * DH + u * 4;
#pragma unroll
    for (int g = 0; g < 4; ++g) {
      u16x4 pk = { f2bf(haccA[g][0] * inv), f2bf(haccA[g][1] * inv),
                   f2bf(haccA[g][2] * inv), f2bf(haccA[g][3] * inv) };
      *(u16x4*)(dst + g * 16) = pk;
    }
  }
  {
    const float inv = 1.0f / lB;
    u16* dst = Hh + ((size_t)b * SEQ + (q0B + lrow)) * DM + h * DH + u * 4;
#pragma unroll
    for (int g = 0; g < 4; ++g) {
      u16x4 pk = { f2bf(haccB[g][0] * inv), f2bf(haccB[g][1] * inv),
                   f2bf(haccB[g][2] * inv), f2bf(haccB[g][3] * inv) };
      *(u16x4*)(dst + g * 16) = pk;
    }
  }
}

extern "C" void kernel_launch(void* const* d_in, const int* in_sizes, int n_in,
                              void* d_out, int out_size, void* d_ws, size_t ws_size,
                              hipStream_t stream) {
  const float* x  = (const float*)d_in[0];
  const float* Wq = (const float*)d_in[1];
  const float* bq = (const float*)d_in[2];
  const float* Wk = (const float*)d_in[3];
  const float* bk = (const float*)d_in[4];
  const float* Wv = (const float*)d_in[5];
  const float* bv = (const float*)d_in[6];
  const float* Wo = (const float*)d_in[7];
  const float* bo = (const float*)d_in[8];
  float* out = (float*)d_out;

  // workspace layout (bytes): total 48 MiB
  char* ws = (char*)d_ws;
  u16* Xb  = (u16*)(ws);                    // 8 MiB  [4096,1024] bf16
  u16* Wt  = (u16*)(ws + (8u << 20));       // 8 MiB  4x [1024,1024] bf16 (transposed)
  u16* Qb  = (u16*)(ws + (16u << 20));      // 8 MiB  [B,H,S,DH]
  u16* Kb  = (u16*)(ws + (24u << 20));      // 8 MiB  [B,H,S,DH]
  u16* Vt  = (u16*)(ws + (32u << 20));      // 8 MiB  [B,H,DH,S]
  u16* Hh  = (u16*)(ws + (40u << 20));      // 8 MiB  [B,S,DM]
  (void)in_sizes; (void)n_in; (void)out_size; (void)ws_size;

  // 1) convert x
  cvt_kernel<<<4096, 256, 0, stream>>>(x, Xb, 4096 * 1024 / 4);
  // 2) transpose+convert weights (one fused launch)
  dim3 tg(32, 32, 4);
  wtrans_kernel<<<tg, 256, 0, stream>>>(Wq, Wk, Wv, Wo, Wt);
  // 3) fused QKV projection
  dim3 gq(8, 32, 3);
  gemm_kernel<<<gq, 256, 0, stream>>>(Xb, Wt, bq, bk, bv, Qb, Kb, Vt, 0);
  // 4) causal flash attention -> Hh [B,S,DM] bf16
  dim3 ga(16, 32);
  attn_kernel<<<ga, 256, 0, stream>>>(Qb, Kb, Vt, Hh);
  // 5) output projection -> fp32 d_out
  dim3 go(8, 32, 1);
  gemm_kernel<<<go, 256, 0, stream>>>(Hh, Wt + (3u << 20), bo, bo, bo, out, out, out, 3);
}